// Round 2
// baseline (910.511 us; speedup 1.0000x reference)
//
#include <hip/hip_runtime.h>

typedef __attribute__((ext_vector_type(8))) short bf16x8;
typedef __attribute__((ext_vector_type(4))) float f32x4;

__device__ __forceinline__ short f2b(float f) {
  unsigned u = __builtin_bit_cast(unsigned, f);
  unsigned r = (u + 0x7FFFu + ((u >> 16) & 1u)) >> 16;
  return (short)r;
}
__device__ __forceinline__ float b2f(short s) {
  unsigned u = ((unsigned)(unsigned short)s) << 16;
  return __builtin_bit_cast(float, u);
}

__device__ __forceinline__ void gload16(const void* g, void* l) {
  __builtin_amdgcn_global_load_lds(
      (const __attribute__((address_space(1))) void*)g,
      (__attribute__((address_space(3))) void*)l, 16, 0, 0);
}

// ---------------- packing kernels ----------------
__global__ void cvt_bf16_vec(const float* __restrict__ src, short* __restrict__ dst, long n) {
  long i = ((long)blockIdx.x * 256 + threadIdx.x) * 8;
  if (i >= n) return;
  f32x4 a = *(const f32x4*)(src + i);
  f32x4 b = *(const f32x4*)(src + i + 4);
  bf16x8 o;
#pragma unroll
  for (int j = 0; j < 4; j++) o[j] = f2b(a[j]);
#pragma unroll
  for (int j = 0; j < 4; j++) o[j + 4] = f2b(b[j]);
  *(bf16x8*)(dst + i) = o;
}

// dst[n*K + k] = bf16(src[k*N + n]);  K = 1<<kbits
__global__ void transpose_cvt(const float* __restrict__ src, short* __restrict__ dst,
                              int kbits, int N) {
  long t = (long)blockIdx.x * 256 + threadIdx.x;
  int K = 1 << kbits;
  if (t >= (long)K * N) return;
  int k = (int)(t & (K - 1));
  int n = (int)(t >> kbits);
  dst[t] = f2b(src[(long)k * N + n]);
}

__global__ void pack_bias3(const float* __restrict__ b0, const float* __restrict__ b1,
                           const float* __restrict__ b2, float* __restrict__ out) {
  int t = blockIdx.x * 256 + threadIdx.x;
  if (t >= 1536) return;
  out[t] = (t < 512) ? b0[t] : ((t < 1024) ? b1[t - 512] : b2[t - 1024]);
}

// ---------------- GEMM: C = A[M][K] @ Bt[N][K]^T  (both bf16) ----------------
// EPI 0: out bf16 = v+bias          (QKV)
// EPI 1: out bf16 = gelu(v+bias)    (fc1)
// EPI 2: out f32  = v+bias+resF     (attn proj + x residual)
// EPI 3: out f32  = v+bias+resB     (fc2 + h residual, bf16 residual)
template <int EPI>
__global__ __launch_bounds__(256, 2) void gemm_bt(
    const short* __restrict__ A, const short* __restrict__ Bt,
    const float* __restrict__ bias, const float* __restrict__ resF,
    const short* __restrict__ resB, void* __restrict__ Cout, int K, int ldc) {
  __shared__ short As[128 * 32];
  __shared__ short Bs[128 * 32];
  const int t = threadIdx.x;
  const int w = t >> 6, lane = t & 63;
  const int lr = lane & 15, lg = lane >> 4;
  const long m0 = (long)blockIdx.y * 128;
  const long n0 = (long)blockIdx.x * 128;
  const int wm = (w >> 1) * 64, wn = (w & 1) * 64;

  f32x4 acc[4][4];
#pragma unroll
  for (int i = 0; i < 4; i++)
#pragma unroll
    for (int j = 0; j < 4; j++) acc[i][j] = f32x4{0.f, 0.f, 0.f, 0.f};

  const int r0 = t >> 2;
  const int kc0 = (t & 3) * 8;
  const short* Ag = A + m0 * K + (long)r0 * K + kc0;
  const short* Bg = Bt + n0 * K + (long)r0 * K + kc0;

  for (int kt = 0; kt < K; kt += 32) {
    gload16(Ag + kt, As + t * 8);
    gload16(Ag + (long)64 * K + kt, As + t * 8 + 2048);
    gload16(Bg + kt, Bs + t * 8);
    gload16(Bg + (long)64 * K + kt, Bs + t * 8 + 2048);
    __syncthreads();
    bf16x8 a[4], b[4];
#pragma unroll
    for (int mi = 0; mi < 4; mi++)
      a[mi] = *(const bf16x8*)(As + (wm + mi * 16 + lr) * 32 + lg * 8);
#pragma unroll
    for (int nj = 0; nj < 4; nj++)
      b[nj] = *(const bf16x8*)(Bs + (wn + nj * 16 + lr) * 32 + lg * 8);
#pragma unroll
    for (int mi = 0; mi < 4; mi++)
#pragma unroll
      for (int nj = 0; nj < 4; nj++)
        acc[mi][nj] =
            __builtin_amdgcn_mfma_f32_16x16x32_bf16(a[mi], b[nj], acc[mi][nj], 0, 0, 0);
    __syncthreads();
  }

#pragma unroll
  for (int mi = 0; mi < 4; mi++)
#pragma unroll
    for (int nj = 0; nj < 4; nj++)
#pragma unroll
      for (int i = 0; i < 4; i++) {
        long row = m0 + wm + mi * 16 + lg * 4 + i;
        int col = (int)n0 + wn + nj * 16 + lr;
        float v = acc[mi][nj][i] + bias[col];
        if (EPI == 0) {
          ((short*)Cout)[row * ldc + col] = f2b(v);
        } else if (EPI == 1) {
          float gl = 0.5f * v * (1.f + erff(v * 0.70710678118654752f));
          ((short*)Cout)[row * ldc + col] = f2b(gl);
        } else if (EPI == 2) {
          ((float*)Cout)[row * ldc + col] = v + resF[row * ldc + col];
        } else {
          ((float*)Cout)[row * ldc + col] = v + b2f(resB[row * ldc + col]);
        }
      }
}

// ---------------- windowed attention ----------------
// grid = nwin windows, 256 threads (4 waves). 8 heads sequential per block.
// Wave w owns query rows [w*16, w*16+16).
__global__ __launch_bounds__(256, 2) void attn_win(const short* __restrict__ QKV,
                                                   short* __restrict__ AO) {
  __shared__ short Vs[64 * 72];  // [j][d], stride 72
  __shared__ short Ps[64 * 72];  // [i][j], stride 72, per-wave row strips
  const int t = threadIdx.x, w = t >> 6, lane = t & 63;
  const int lr = lane & 15, lg = lane >> 4;
  const long base = (long)blockIdx.x * 64 * 1536;
  const long obase = (long)blockIdx.x * 64 * 512;

  for (int h = 0; h < 8; h++) {
    const int co = h * 64;
    // stage V[j][d] cooperatively: 512 16B chunks
#pragma unroll
    for (int it = 0; it < 2; it++) {
      int c = t + it * 256;
      int j = c >> 3, d0 = (c & 7) * 8;
      *(bf16x8*)(Vs + j * 72 + d0) =
          *(const bf16x8*)(QKV + base + (long)j * 1536 + 1024 + co + d0);
    }
    __syncthreads();

    // Q (own 16-row strip) and K (all 64) fragments straight from global
    bf16x8 qf[2], kf[4][2];
#pragma unroll
    for (int kb = 0; kb < 2; kb++)
      qf[kb] = *(const bf16x8*)(QKV + base + (long)(w * 16 + lr) * 1536 + co + kb * 32 + lg * 8);
#pragma unroll
    for (int nj = 0; nj < 4; nj++)
#pragma unroll
      for (int kb = 0; kb < 2; kb++)
        kf[nj][kb] = *(const bf16x8*)(QKV + base + (long)(nj * 16 + lr) * 1536 + 512 + co +
                                      kb * 32 + lg * 8);

    // S = (Q K^T) * 1/8
    f32x4 s[4];
#pragma unroll
    for (int nj = 0; nj < 4; nj++) {
      s[nj] = f32x4{0.f, 0.f, 0.f, 0.f};
      s[nj] = __builtin_amdgcn_mfma_f32_16x16x32_bf16(qf[0], kf[nj][0], s[nj], 0, 0, 0);
      s[nj] = __builtin_amdgcn_mfma_f32_16x16x32_bf16(qf[1], kf[nj][1], s[nj], 0, 0, 0);
      s[nj] = s[nj] * 0.125f;
    }

    // softmax over keys: row = w*16 + lg*4 + i; cols spread over (nj, lr)
#pragma unroll
    for (int i = 0; i < 4; i++) {
      float mx = fmaxf(fmaxf(s[0][i], s[1][i]), fmaxf(s[2][i], s[3][i]));
#pragma unroll
      for (int off = 1; off < 16; off <<= 1) mx = fmaxf(mx, __shfl_xor(mx, off, 64));
      float sum = 0.f;
#pragma unroll
      for (int nj = 0; nj < 4; nj++) {
        float p = __expf(s[nj][i] - mx);
        s[nj][i] = p;
        sum += p;
      }
#pragma unroll
      for (int off = 1; off < 16; off <<= 1) sum += __shfl_xor(sum, off, 64);
      float inv = 1.f / sum;
#pragma unroll
      for (int nj = 0; nj < 4; nj++) s[nj][i] *= inv;
    }

    // P: C-layout -> LDS -> A-layout (bf16)
#pragma unroll
    for (int nj = 0; nj < 4; nj++)
#pragma unroll
      for (int i = 0; i < 4; i++)
        Ps[(w * 16 + lg * 4 + i) * 72 + nj * 16 + lr] = f2b(s[nj][i]);

    bf16x8 pa[2];
#pragma unroll
    for (int kb = 0; kb < 2; kb++)
      pa[kb] = *(const bf16x8*)(Ps + (w * 16 + lr) * 72 + kb * 32 + lg * 8);

    // O = P V
    f32x4 o[4];
#pragma unroll
    for (int nb = 0; nb < 4; nb++) o[nb] = f32x4{0.f, 0.f, 0.f, 0.f};
#pragma unroll
    for (int kb = 0; kb < 2; kb++)
#pragma unroll
      for (int nb = 0; nb < 4; nb++) {
        bf16x8 vb;
#pragma unroll
        for (int jj = 0; jj < 8; jj++)
          vb[jj] = Vs[(kb * 32 + lg * 8 + jj) * 72 + nb * 16 + lr];
        o[nb] = __builtin_amdgcn_mfma_f32_16x16x32_bf16(pa[kb], vb, o[nb], 0, 0, 0);
      }

#pragma unroll
    for (int nb = 0; nb < 4; nb++)
#pragma unroll
      for (int i = 0; i < 4; i++)
        AO[obase + (long)(w * 16 + lg * 4 + i) * 512 + co + nb * 16 + lr] = f2b(o[nb][i]);
    __syncthreads();
  }
}

// ---------------- LayerNorm over C=512, one row per wave ----------------
template <int OUTB>
__global__ __launch_bounds__(256, 4) void ln_rows(const float* __restrict__ Y,
                                                  const float* __restrict__ gamma,
                                                  const float* __restrict__ beta,
                                                  short* __restrict__ Hb,
                                                  float* __restrict__ Of) {
  const int w = threadIdx.x >> 6, lane = threadIdx.x & 63;
  const long row = (long)blockIdx.x * 4 + w;
  const float* y = Y + row * 512 + lane * 8;
  f32x4 a = *(const f32x4*)(y);
  f32x4 b = *(const f32x4*)(y + 4);
  float s = a[0] + a[1] + a[2] + a[3] + b[0] + b[1] + b[2] + b[3];
  float s2 = a[0] * a[0] + a[1] * a[1] + a[2] * a[2] + a[3] * a[3] + b[0] * b[0] +
             b[1] * b[1] + b[2] * b[2] + b[3] * b[3];
#pragma unroll
  for (int off = 1; off < 64; off <<= 1) {
    s += __shfl_xor(s, off, 64);
    s2 += __shfl_xor(s2, off, 64);
  }
  float mu = s * (1.f / 512.f);
  float var = s2 * (1.f / 512.f) - mu * mu;
  float rstd = rsqrtf(fmaxf(var, 0.f) + 1e-12f);
  const int c0 = lane * 8;
  f32x4 ga = *(const f32x4*)(gamma + c0), gb = *(const f32x4*)(gamma + c0 + 4);
  f32x4 ba = *(const f32x4*)(beta + c0), bb = *(const f32x4*)(beta + c0 + 4);
  if (OUTB) {
    bf16x8 o;
#pragma unroll
    for (int j = 0; j < 4; j++) o[j] = f2b(ga[j] * ((a[j] - mu) * rstd) + ba[j]);
#pragma unroll
    for (int j = 0; j < 4; j++) o[j + 4] = f2b(gb[j] * ((b[j] - mu) * rstd) + bb[j]);
    *(bf16x8*)(Hb + row * 512 + c0) = o;
  } else {
    f32x4 o0, o1;
#pragma unroll
    for (int j = 0; j < 4; j++) o0[j] = ga[j] * ((a[j] - mu) * rstd) + ba[j];
#pragma unroll
    for (int j = 0; j < 4; j++) o1[j] = gb[j] * ((b[j] - mu) * rstd) + bb[j];
    *(f32x4*)(Of + row * 512 + c0) = o0;
    *(f32x4*)(Of + row * 512 + c0 + 4) = o1;
  }
}

// ---------------- driver ----------------
extern "C" void kernel_launch(void* const* d_in, const int* in_sizes, int n_in,
                              void* d_out, int out_size, void* d_ws, size_t ws_size,
                              hipStream_t stream) {
  (void)in_sizes; (void)n_in; (void)out_size;
  const float* x = (const float*)d_in[0];
  const float* wq = (const float*)d_in[1];
  const float* bq = (const float*)d_in[2];
  const float* wk = (const float*)d_in[3];
  const float* bk = (const float*)d_in[4];
  const float* wv = (const float*)d_in[5];
  const float* bv = (const float*)d_in[6];
  const float* wo = (const float*)d_in[7];
  const float* bo = (const float*)d_in[8];
  const float* g1 = (const float*)d_in[9];
  const float* be1 = (const float*)d_in[10];
  const float* wfc1 = (const float*)d_in[11];
  const float* bfc1 = (const float*)d_in[12];
  const float* wfc2 = (const float*)d_in[13];
  const float* bfc2 = (const float*)d_in[14];
  const float* g2 = (const float*)d_in[15];
  const float* be2 = (const float*)d_in[16];

  const long T = 65536;
  char* ws = (char*)d_ws;

  // ---- weights at offset 0 (~6.3 MiB) ----
  short* WQKVT = (short*)(ws);                 // [1536][512]
  short* WOT = WQKVT + 1536 * 512;             // [512][512]
  short* WFC1T = WOT + 512 * 512;              // [2048][512]
  short* WFC2T = WFC1T + 2048 * 512;           // [512][2048]
  float* BQKV = (float*)(WFC2T + 512 * 2048);  // [1536]
  size_t woff = ((size_t)((char*)(BQKV + 1536) - ws) + 255) & ~(size_t)255;

  // ---- adaptive chunking: per-token buffer need = 4096 + 2048 + 1024 B ----
  size_t avail = (ws_size > woff) ? (ws_size - woff) : 0;
  long Tc = T;
  while (Tc > 128 && (size_t)Tc * 7168 > avail) Tc >>= 1;
  const long nch = T / Tc;

  char* R0 = ws + woff;                 // QKV bf16 [Tc][1536] -> Y1 f32 [Tc][512] -> FF1 bf16 [Tc][2048]
  char* R1 = R0 + (size_t)Tc * 4096;    // XB bf16 [Tc][512] -> AO bf16 -> Y2 f32 [Tc][512]
  char* R2 = R1 + (size_t)Tc * 2048;    // H bf16 [Tc][512]

  short* QKV = (short*)R0;
  float* Y1 = (float*)R0;
  short* FF1 = (short*)R0;
  short* XB = (short*)R1;
  short* AO = (short*)R1;
  float* Y2 = (float*)R1;
  short* H = (short*)R2;

  // ---- pack weights once per call ----
  transpose_cvt<<<1024, 256, 0, stream>>>(wq, WQKVT, 9, 512);
  transpose_cvt<<<1024, 256, 0, stream>>>(wk, WQKVT + 512 * 512, 9, 512);
  transpose_cvt<<<1024, 256, 0, stream>>>(wv, WQKVT + 1024 * 512, 9, 512);
  transpose_cvt<<<1024, 256, 0, stream>>>(wo, WOT, 9, 512);
  transpose_cvt<<<4096, 256, 0, stream>>>(wfc1, WFC1T, 9, 2048);
  transpose_cvt<<<4096, 256, 0, stream>>>(wfc2, WFC2T, 11, 512);
  pack_bias3<<<6, 256, 0, stream>>>(bq, bk, bv, BQKV);

  for (long c = 0; c < nch; c++) {
    const long t0 = c * Tc;
    const int mb = (int)(Tc / 128);
    // x chunk -> bf16
    cvt_bf16_vec<<<(int)(Tc / 4), 256, 0, stream>>>(x + t0 * 512, XB, Tc * 512);
    // QKV projection
    gemm_bt<0><<<dim3(12, mb), 256, 0, stream>>>(XB, WQKVT, BQKV, nullptr, nullptr,
                                                 (void*)QKV, 512, 1536);
    // windowed attention
    attn_win<<<(int)(Tc / 64), 256, 0, stream>>>(QKV, AO);
    // output projection + x residual -> Y1 f32
    gemm_bt<2><<<dim3(4, mb), 256, 0, stream>>>(AO, WOT, bo, x + t0 * 512, nullptr,
                                                (void*)Y1, 512, 512);
    // LN1 -> H bf16
    ln_rows<1><<<(int)(Tc / 4), 256, 0, stream>>>(Y1, g1, be1, H, nullptr);
    // fc1 + GELU -> FF1 bf16
    gemm_bt<1><<<dim3(16, mb), 256, 0, stream>>>(H, WFC1T, bfc1, nullptr, nullptr,
                                                 (void*)FF1, 512, 2048);
    // fc2 + h residual -> Y2 f32
    gemm_bt<3><<<dim3(4, mb), 256, 0, stream>>>(FF1, WFC2T, bfc2, nullptr, H, (void*)Y2,
                                                2048, 512);
    // LN2 -> output f32
    ln_rows<0><<<(int)(Tc / 4), 256, 0, stream>>>(Y2, g2, be2, nullptr,
                                                  (float*)d_out + t0 * 512);
  }
}